// Round 5
// baseline (1696.070 us; speedup 1.0000x reference)
//
#include <hip/hip_runtime.h>
#include <hip/hip_bf16.h>

static constexpr int NN  = 50000;
static constexpr int EA  = 250000;   // r1, r2
static constexpr int EB  = 500000;   // r3, neg
static constexpr int LD1 = 264;      // padded x1/agg row stride (16B-aligned rows)

// ---------------- utility: zero 32-bit words ----------------
__global__ void k_zero(unsigned int* __restrict__ p, int n) {
    int i = blockIdx.x * 256 + threadIdx.x;
    if (i < n) p[i] = 0u;
}

// ---------------- CSR build ----------------
__global__ void k_count(const int* __restrict__ dst, int E, int* __restrict__ deg) {
    int e = blockIdx.x * blockDim.x + threadIdx.x;
    if (e < E) atomicAdd(&deg[dst[e]], 1);
}

__global__ __launch_bounds__(1024) void k_scan4(const int* __restrict__ deg4,
                                                int* __restrict__ rp4,
                                                int* __restrict__ cur4, int n) {
    const int* deg = deg4 + (size_t)blockIdx.x * n;
    int* rp  = rp4  + (size_t)blockIdx.x * (n + 1);
    int* cur = cur4 + (size_t)blockIdx.x * n;
    __shared__ int wsum[16];
    __shared__ int srun;
    int tid = threadIdx.x;
    int lane = tid & 63, wid = tid >> 6;
    if (tid == 0) srun = 0;
    __syncthreads();
    for (int base = 0; base < n; base += 1024) {
        int i = base + tid;
        int v = (i < n) ? deg[i] : 0;
        int incl = v;
        #pragma unroll
        for (int d = 1; d < 64; d <<= 1) {
            int y = __shfl_up(incl, d, 64);
            if (lane >= d) incl += y;
        }
        if (lane == 63) wsum[wid] = incl;
        __syncthreads();
        if (wid == 0 && lane < 16) {
            int w = wsum[lane];
            #pragma unroll
            for (int d = 1; d < 16; d <<= 1) {
                int y = __shfl_up(w, d, 64);
                if (lane >= d) w += y;
            }
            wsum[lane] = w;
        }
        __syncthreads();
        int run  = srun;
        int woff = (wid > 0) ? wsum[wid - 1] : 0;
        int ex   = run + woff + incl - v;
        if (i < n) { rp[i] = ex; cur[i] = ex; }
        int total = wsum[15];
        __syncthreads();
        if (tid == 0) srun = run + total;
        __syncthreads();
    }
    if (tid == 0) rp[n] = srun;
}

__global__ void k_scatter(const int* __restrict__ src, const int* __restrict__ dst, int E,
                          int* __restrict__ cur, int* __restrict__ col) {
    int e = blockIdx.x * blockDim.x + threadIdx.x;
    if (e < E) {
        int p = atomicAdd(&cur[dst[e]], 1);
        col[p] = src[e];
    }
}

// ---------------- fc1 (K=18, reads x[:,1:19]) ----------------
__global__ __launch_bounds__(256) void k_fc1(const float* __restrict__ x,
                                             const float* __restrict__ W,
                                             const float* __restrict__ bias,
                                             float* __restrict__ out) {
    __shared__ float sx[8][20];
    int tid = threadIdx.x;
    int n0 = blockIdx.x * 8;
    for (int i = tid; i < 8 * 19; i += 256) {
        int m = i / 19, k = i % 19;
        sx[m][k] = x[(size_t)(n0 + m) * 19 + k];
    }
    __syncthreads();
    float wr[18];
    #pragma unroll
    for (int k = 0; k < 18; ++k) wr[k] = W[k * 256 + tid];
    float bv = bias[tid];
    #pragma unroll
    for (int m = 0; m < 8; ++m) {
        float acc = bv;
        #pragma unroll
        for (int k = 0; k < 18; ++k) acc = fmaf(sx[m][k + 1], wr[k], acc);
        out[(size_t)(n0 + m) * 256 + tid] = fmaxf(acc, 0.f);
    }
}

// ---------------- generic fp32 GEMM: C = act(A1@W1 [+ A2@W2] + bias) ----------------
// BM=64, BN=128, BK=8; 256 threads; per-thread 4x8 accumulators.
// If vdot != null: dotout[row] += sum_col act(...)*vdot[col] instead of storing C.
__global__ __launch_bounds__(256) void k_gemm(
    const float* __restrict__ A1, int lda1, int K1, const float* __restrict__ W1,
    const float* __restrict__ A2, int lda2, int K2, const float* __restrict__ W2,
    const float* __restrict__ bias, int ldw,
    float* __restrict__ C, int ldc, int M, int relu,
    const float* __restrict__ vdot, float* __restrict__ dotout)
{
    __shared__ float As[8][64];
    __shared__ float Ws[8][128];
    int tid = threadIdx.x;
    int tx = tid & 15, ty = tid >> 4;
    int row0 = blockIdx.y * 64;
    int col0 = blockIdx.x * 128;
    float acc[4][8];
    #pragma unroll
    for (int i = 0; i < 4; ++i)
        #pragma unroll
        for (int j = 0; j < 8; ++j) acc[i][j] = 0.f;

    #pragma unroll 1
    for (int panel = 0; panel < 2; ++panel) {
        const float* A = panel ? A2 : A1;
        const float* W = panel ? W2 : W1;
        int lda = panel ? lda2 : lda1;
        int K   = panel ? K2   : K1;
        if (A == nullptr) continue;
        #pragma unroll 1
        for (int kb = 0; kb < K; kb += 8) {
            if (tid < 128) {
                int r = tid >> 1, q = tid & 1;
                int row = row0 + r;
                float4 v = make_float4(0.f, 0.f, 0.f, 0.f);
                if (row < M) v = *(const float4*)(A + (size_t)row * lda + kb + q * 4);
                As[q * 4 + 0][r] = v.x;
                As[q * 4 + 1][r] = v.y;
                As[q * 4 + 2][r] = v.z;
                As[q * 4 + 3][r] = v.w;
            }
            {
                int k = tid >> 5, c = tid & 31;
                float4 v = *(const float4*)(W + (size_t)(kb + k) * ldw + col0 + c * 4);
                *(float4*)&Ws[k][c * 4] = v;
            }
            __syncthreads();
            #pragma unroll
            for (int kk = 0; kk < 8; ++kk) {
                float4 a  = *(const float4*)&As[kk][ty * 4];
                float4 w0 = *(const float4*)&Ws[kk][tx * 8];
                float4 w1 = *(const float4*)&Ws[kk][tx * 8 + 4];
                float av[4] = {a.x, a.y, a.z, a.w};
                float wv[8] = {w0.x, w0.y, w0.z, w0.w, w1.x, w1.y, w1.z, w1.w};
                #pragma unroll
                for (int i = 0; i < 4; ++i)
                    #pragma unroll
                    for (int j = 0; j < 8; ++j)
                        acc[i][j] = fmaf(av[i], wv[j], acc[i][j]);
            }
            __syncthreads();
        }
    }
    float bv[8];
    #pragma unroll
    for (int j = 0; j < 8; ++j) bv[j] = bias ? bias[col0 + tx * 8 + j] : 0.f;

    if (vdot) {
        float vv[8];
        #pragma unroll
        for (int j = 0; j < 8; ++j) vv[j] = vdot[col0 + tx * 8 + j];
        #pragma unroll
        for (int i = 0; i < 4; ++i) {
            int row = row0 + ty * 4 + i;
            float part = 0.f;
            #pragma unroll
            for (int j = 0; j < 8; ++j) {
                float v = acc[i][j] + bv[j];
                v = relu ? fmaxf(v, 0.f) : v;
                part = fmaf(v, vv[j], part);
            }
            #pragma unroll
            for (int d = 1; d < 16; d <<= 1) part += __shfl_xor(part, d, 64);
            if (tx == 0 && row < M) atomicAdd(&dotout[row], part);
        }
        return;
    }

    #pragma unroll
    for (int i = 0; i < 4; ++i) {
        int row = row0 + ty * 4 + i;
        if (row < M) {
            float o[8];
            #pragma unroll
            for (int j = 0; j < 8; ++j) {
                float v = acc[i][j] + bv[j];
                o[j] = relu ? fmaxf(v, 0.f) : v;
            }
            *(float4*)(C + (size_t)row * ldc + col0 + tx * 8)     = make_float4(o[0], o[1], o[2], o[3]);
            *(float4*)(C + (size_t)row * ldc + col0 + tx * 8 + 4) = make_float4(o[4], o[5], o[6], o[7]);
        }
    }
}

// ---------------- GAT (scalar feature, wave per node, 4 channels/lane) ----------------
__global__ __launch_bounds__(256) void k_gat(
    const float* __restrict__ x,
    const int* __restrict__ rp, const int* __restrict__ col,
    const float* __restrict__ gw, const float* __restrict__ gas,
    const float* __restrict__ gad, const float* __restrict__ gb,
    float* __restrict__ x1, int outcol)
{
    int lane = threadIdx.x & 63;
    int node = blockIdx.x * 4 + (threadIdx.x >> 6);
    if (node >= NN) return;
    int beg = rp[node], end = rp[node + 1];
    float bias = gb[0];
    float res;
    if (end == beg) {
        res = fmaxf(bias, 0.f);   // empty segment: out row = 0, mean 0, +b, relu
    } else {
        float maxa = -3.4e38f, mina = 3.4e38f;
        for (int e = beg + lane; e < end; e += 64) {
            float a = x[(size_t)col[e] * 19];
            maxa = fmaxf(maxa, a);
            mina = fminf(mina, a);
        }
        #pragma unroll
        for (int d = 32; d >= 1; d >>= 1) {
            maxa = fmaxf(maxa, __shfl_xor(maxa, d, 64));
            mina = fminf(mina, __shfl_xor(mina, d, 64));
        }
        float b = x[(size_t)node * 19];
        float w[4], u[4], cc[4];
        #pragma unroll
        for (int j = 0; j < 4; ++j) {
            float wv = gw[lane * 4 + j];
            w[j]  = wv;
            u[j]  = wv * gas[lane * 4 + j];
            cc[j] = b * wv * gad[lane * 4 + j];
        }
        float m[4], s[4], t[4];
        #pragma unroll
        for (int j = 0; j < 4; ++j) {
            float sel = (u[j] >= 0.f) ? maxa : mina;   // lrelu & a*u+c monotone -> exact max
            float mm = fmaf(sel, u[j], cc[j]);
            m[j] = (mm >= 0.f) ? mm : 0.2f * mm;
            s[j] = 0.f; t[j] = 0.f;
        }
        for (int e = beg; e < end; ++e) {
            float a = x[(size_t)col[e] * 19];
            #pragma unroll
            for (int j = 0; j < 4; ++j) {
                float al = fmaf(a, u[j], cc[j]);
                al = (al >= 0.f) ? al : 0.2f * al;
                float p = __expf(al - m[j]);
                s[j] += p;
                t[j] += p * a;
            }
        }
        float part = 0.f;
        #pragma unroll
        for (int j = 0; j < 4; ++j) part += w[j] * t[j] / (s[j] + 1e-16f);
        #pragma unroll
        for (int d = 32; d >= 1; d >>= 1) part += __shfl_xor(part, d, 64);
        res = fmaxf(part * (1.f / 256.f) + bias, 0.f);
    }
    if (lane == 0) x1[(size_t)node * LD1 + outcol] = res;
}

// ---------------- SAGE mean-aggregate (wave per node, float4 gather) ----------------
__global__ __launch_bounds__(256) void k_sage_agg(
    const float* __restrict__ x1, const int* __restrict__ rp, const int* __restrict__ col,
    float* __restrict__ agg)
{
    int lane = threadIdx.x & 63;
    int node = blockIdx.x * 4 + (threadIdx.x >> 6);
    if (node >= NN) return;
    int beg = rp[node], end = rp[node + 1];
    float inv = 1.f / fmaxf((float)(end - beg), 1.f);
    for (int ch = lane; ch < LD1 / 4; ch += 64) {
        float ax = 0.f, ay = 0.f, az = 0.f, aw = 0.f;
        for (int e = beg; e < end; ++e) {
            const float4 v = *(const float4*)(x1 + (size_t)col[e] * LD1 + ch * 4);
            ax += v.x; ay += v.y; az += v.z; aw += v.w;
        }
        *(float4*)(agg + (size_t)node * LD1 + ch * 4) = make_float4(ax * inv, ay * inv, az * inv, aw * inv);
    }
}

// ---------------- finalize: dots + bias -> float32 out ----------------
__global__ void k_final(const float* __restrict__ dots,
                        const float* __restrict__ b6, const float* __restrict__ b7,
                        float* __restrict__ out) {
    int i = blockIdx.x * 256 + threadIdx.x;
    if (i >= 2 * NN) return;
    float b = (i < NN) ? b6[0] : b7[0];
    out[i] = dots[i] + b;
}

// ---------------- weight repacks ----------------
__global__ void k_cat3(const float* __restrict__ s0, const float* __restrict__ s1,
                       const float* __restrict__ s2, float* __restrict__ dst) {
    // dst: (264,384); srcs: (259,128) each; pad rows 259..263 with 0
    int idx = blockIdx.x * 256 + threadIdx.x;
    if (idx >= 264 * 384) return;
    int k = idx / 384, c = idx % 384;
    float v = 0.f;
    if (k < 259) {
        const float* s = (c < 128) ? s0 : (c < 256) ? s1 : s2;
        v = s[k * 128 + (c & 127)];
    }
    dst[idx] = v;
}

__global__ void k_pad_w(const float* __restrict__ s, float* __restrict__ dst) {
    // dst: (264,256); src: (259,256)
    int idx = blockIdx.x * 256 + threadIdx.x;
    if (idx >= 264 * 256) return;
    int k = idx / 256, c = idx % 256;
    dst[idx] = (k < 259) ? s[k * 256 + c] : 0.f;
}

__global__ void k_pad_x1(float* __restrict__ x1) {
    int idx = blockIdx.x * 256 + threadIdx.x;
    if (idx >= NN * 5) return;
    int node = idx / 5, c = idx % 5;
    x1[(size_t)node * LD1 + 259 + c] = 0.f;
}

extern "C" void kernel_launch(void* const* d_in, const int* in_sizes, int n_in,
                              void* d_out, int out_size, void* d_ws, size_t ws_size,
                              hipStream_t stream)
{
    (void)in_sizes; (void)n_in; (void)out_size; (void)ws_size;
    const float* x      = (const float*)d_in[0];
    const float* fc1_w  = (const float*)d_in[1];
    const float* fc1_b  = (const float*)d_in[2];
    const float* fc2_w  = (const float*)d_in[3];
    const float* fc2_b  = (const float*)d_in[4];
    const float* fc3_w  = (const float*)d_in[5];
    const float* fc3_b  = (const float*)d_in[6];
    const float* g_w[3]  = {(const float*)d_in[7],  (const float*)d_in[11], (const float*)d_in[15]};
    const float* g_as[3] = {(const float*)d_in[8],  (const float*)d_in[12], (const float*)d_in[16]};
    const float* g_ad[3] = {(const float*)d_in[9],  (const float*)d_in[13], (const float*)d_in[17]};
    const float* g_b[3]  = {(const float*)d_in[10], (const float*)d_in[14], (const float*)d_in[18]};
    const float* sg_wl[3] = {(const float*)d_in[19], (const float*)d_in[21], (const float*)d_in[23]};
    const float* sg_wr[3] = {(const float*)d_in[20], (const float*)d_in[22], (const float*)d_in[24]};
    const float* c21_wl = (const float*)d_in[25];
    const float* c21_wr = (const float*)d_in[26];
    const float* fc4_w  = (const float*)d_in[27];
    const float* fc4_b  = (const float*)d_in[28];
    const float* fc4n_w = (const float*)d_in[29];
    const float* fc4n_b = (const float*)d_in[30];
    const float* fc5_w  = (const float*)d_in[31];
    const float* fc5_b  = (const float*)d_in[32];
    const float* fc6_w  = (const float*)d_in[33];
    const float* fc6_b  = (const float*)d_in[34];
    const float* fc7_w  = (const float*)d_in[35];
    const float* fc7_b  = (const float*)d_in[36];
    const int* eidx[4] = {(const int*)d_in[37], (const int*)d_in[38], (const int*)d_in[39], (const int*)d_in[40]};
    const int  ecnt[4] = {EA, EA, EB, EB};

    // ---- workspace layout (floats then ints), ~192 MB total ----
    float* fws = (float*)d_ws;
    size_t off = 0;
    float* x1     = fws + off; off += (size_t)NN * LD1;   // [x3 | p1 p2 p3 | pad]
    float* bufA   = fws + off; off += (size_t)NN * LD1;   // h / agg
    float* bufB   = fws + off; off += (size_t)NN * 384;   // h / s / xn
    float* wlcat  = fws + off; off += 264 * 384;
    float* wrcat  = fws + off; off += 264 * 384;
    float* c21wlp = fws + off; off += 264 * 256;
    float* c21wrp = fws + off; off += 264 * 256;
    float* dots   = fws + off; off += 2 * NN;             // [y | xn] pre-bias dots
    int* deg4 = (int*)(fws + off);
    int* rp4  = deg4 + 4 * NN;
    int* cur4 = rp4 + 4 * (NN + 1);
    int* colx = cur4 + 4 * NN;
    int* colg[4] = {colx, colx + EA, colx + 2 * EA, colx + 2 * EA + EB};

    float* outy = (float*)d_out;   // reference output dtype: float32

    // ---- zero deg counters + dot scratch (ws is poisoned each launch) ----
    k_zero<<<(4 * NN + 255) / 256, 256, 0, stream>>>((unsigned int*)deg4, 4 * NN);
    k_zero<<<(2 * NN + 255) / 256, 256, 0, stream>>>((unsigned int*)dots, 2 * NN);

    // ---- CSR build for 4 graphs (0=r1, 1=r2, 2=r3, 3=neg) ----
    for (int g = 0; g < 4; ++g)
        k_count<<<(ecnt[g] + 255) / 256, 256, 0, stream>>>(eidx[g] + ecnt[g], ecnt[g], deg4 + g * NN);
    k_scan4<<<4, 1024, 0, stream>>>(deg4, rp4, cur4, NN);
    for (int g = 0; g < 4; ++g)
        k_scatter<<<(ecnt[g] + 255) / 256, 256, 0, stream>>>(eidx[g], eidx[g] + ecnt[g], ecnt[g],
                                                             cur4 + g * NN, colg[g]);

    // ---- weight repacks ----
    k_cat3<<<(264 * 384 + 255) / 256, 256, 0, stream>>>(sg_wl[0], sg_wl[1], sg_wl[2], wlcat);
    k_cat3<<<(264 * 384 + 255) / 256, 256, 0, stream>>>(sg_wr[0], sg_wr[1], sg_wr[2], wrcat);
    k_pad_w<<<(264 * 256 + 255) / 256, 256, 0, stream>>>(c21_wl, c21wlp);
    k_pad_w<<<(264 * 256 + 255) / 256, 256, 0, stream>>>(c21_wr, c21wrp);

    // ---- MLP head: fc1 -> fc2 -> fc3 (into x1 cols 0..255) ----
    k_fc1<<<NN / 8, 256, 0, stream>>>(x, fc1_w, fc1_b, bufA);
    dim3 gB(2, (NN + 63) / 64);
    k_gemm<<<gB, 256, 0, stream>>>(bufA, 256, 256, fc2_w, nullptr, 0, 0, nullptr, fc2_b, 256,
                                   bufB, 256, NN, 1, nullptr, nullptr);
    k_gemm<<<gB, 256, 0, stream>>>(bufB, 256, 256, fc3_w, nullptr, 0, 0, nullptr, fc3_b, 256,
                                   x1, LD1, NN, 1, nullptr, nullptr);
    k_pad_x1<<<(NN * 5 + 255) / 256, 256, 0, stream>>>(x1);

    // ---- GATs -> x1 cols 256,257,258 ----
    for (int g = 0; g < 3; ++g)
        k_gat<<<NN / 4, 256, 0, stream>>>(x, rp4 + g * (NN + 1), colg[g],
                                          g_w[g], g_as[g], g_ad[g], g_b[g], x1, 256 + g);

    // ---- xn path: neg-SAGE -> fc4n(+relu) -> fused fc7 dot ----
    k_sage_agg<<<NN / 4, 256, 0, stream>>>(x1, rp4 + 3 * (NN + 1), colg[3], bufA);
    k_gemm<<<gB, 256, 0, stream>>>(bufA, LD1, LD1, c21wlp, x1, LD1, LD1, c21wrp, nullptr, 256,
                                   bufB, 256, NN, 1, nullptr, nullptr);
    k_gemm<<<gB, 256, 0, stream>>>(bufB, 256, 256, fc4n_w, nullptr, 0, 0, nullptr, fc4n_b, 256,
                                   nullptr, 0, NN, 1, fc7_w, dots + NN);

    // ---- y path: r3-SAGE (3 layers fused) -> fc4 -> fused fc5+fc6 dot ----
    k_sage_agg<<<NN / 4, 256, 0, stream>>>(x1, rp4 + 2 * (NN + 1), colg[2], bufA);
    dim3 gS(3, (NN + 63) / 64);
    k_gemm<<<gS, 256, 0, stream>>>(bufA, LD1, LD1, wlcat, x1, LD1, LD1, wrcat, nullptr, 384,
                                   bufB, 384, NN, 1, nullptr, nullptr);
    k_gemm<<<gB, 256, 0, stream>>>(bufB, 384, 384, fc4_w, nullptr, 0, 0, nullptr, fc4_b, 256,
                                   bufA, 256, NN, 1, nullptr, nullptr);
    k_gemm<<<gB, 256, 0, stream>>>(bufA, 256, 256, fc5_w, nullptr, 0, 0, nullptr, fc5_b, 256,
                                   nullptr, 0, NN, 1, fc6_w, dots);

    // ---- finalize both outputs (float32) ----
    k_final<<<(2 * NN + 255) / 256, 256, 0, stream>>>(dots, fc6_b, fc7_b, outy);
}

// Round 6
// 921.518 us; speedup vs baseline: 1.8405x; 1.8405x over previous
//
#include <hip/hip_runtime.h>
#include <hip/hip_bf16.h>

typedef __hip_bfloat16 bf16;
typedef __attribute__((ext_vector_type(8))) short bfrag;   // 8 bf16 = 4 VGPRs
typedef __attribute__((ext_vector_type(4))) float f32x4;

static constexpr int NN  = 50000;
static constexpr int EA  = 250000;   // r1, r2
static constexpr int EB  = 500000;   // r3, neg
static constexpr int LDX = 288;      // x1/agg row stride in bf16 (576 B, 16B-aligned)

__device__ __forceinline__ float b2f(unsigned int u) { return __uint_as_float((u & 0xffffu) << 16); }
__device__ __forceinline__ unsigned short f2b(float f) {
    bf16 h = __float2bfloat16(f);
    return *reinterpret_cast<unsigned short*>(&h);
}
__device__ __forceinline__ void gload16(const void* g, void* l) {
    __builtin_amdgcn_global_load_lds((const __attribute__((address_space(1))) void*)g,
                                     (__attribute__((address_space(3))) void*)l, 16, 0, 0);
}

// ---------------- utility: zero 32-bit words ----------------
__global__ void k_zero(unsigned int* __restrict__ p, int n) {
    int i = blockIdx.x * 256 + threadIdx.x;
    if (i < n) p[i] = 0u;
}

// ---------------- CSR build ----------------
__global__ void k_count(const int* __restrict__ dst, int E, int* __restrict__ deg) {
    int e = blockIdx.x * blockDim.x + threadIdx.x;
    if (e < E) atomicAdd(&deg[dst[e]], 1);
}

__global__ __launch_bounds__(1024) void k_scan4(const int* __restrict__ deg4,
                                                int* __restrict__ rp4,
                                                int* __restrict__ cur4, int n) {
    const int* deg = deg4 + (size_t)blockIdx.x * n;
    int* rp  = rp4  + (size_t)blockIdx.x * (n + 1);
    int* cur = cur4 + (size_t)blockIdx.x * n;
    __shared__ int wsum[16];
    __shared__ int srun;
    int tid = threadIdx.x;
    int lane = tid & 63, wid = tid >> 6;
    if (tid == 0) srun = 0;
    __syncthreads();
    for (int base = 0; base < n; base += 1024) {
        int i = base + tid;
        int v = (i < n) ? deg[i] : 0;
        int incl = v;
        #pragma unroll
        for (int d = 1; d < 64; d <<= 1) {
            int y = __shfl_up(incl, d, 64);
            if (lane >= d) incl += y;
        }
        if (lane == 63) wsum[wid] = incl;
        __syncthreads();
        if (wid == 0 && lane < 16) {
            int w = wsum[lane];
            #pragma unroll
            for (int d = 1; d < 16; d <<= 1) {
                int y = __shfl_up(w, d, 64);
                if (lane >= d) w += y;
            }
            wsum[lane] = w;
        }
        __syncthreads();
        int run  = srun;
        int woff = (wid > 0) ? wsum[wid - 1] : 0;
        int ex   = run + woff + incl - v;
        if (i < n) { rp[i] = ex; cur[i] = ex; }
        int total = wsum[15];
        __syncthreads();
        if (tid == 0) srun = run + total;
        __syncthreads();
    }
    if (tid == 0) rp[n] = srun;
}

__global__ void k_scatter(const int* __restrict__ src, const int* __restrict__ dst, int E,
                          int* __restrict__ cur, int* __restrict__ col) {
    int e = blockIdx.x * blockDim.x + threadIdx.x;
    if (e < E) {
        int p = atomicAdd(&cur[dst[e]], 1);
        col[p] = src[e];
    }
}

// ---------------- fc1 (K=18, reads x[:,1:19] fp32) -> bf16 out ----------------
__global__ __launch_bounds__(256) void k_fc1(const float* __restrict__ x,
                                             const float* __restrict__ W,
                                             const float* __restrict__ bias,
                                             bf16* __restrict__ out) {
    __shared__ float sx[8][20];
    int tid = threadIdx.x;
    int n0 = blockIdx.x * 8;
    for (int i = tid; i < 8 * 19; i += 256) {
        int m = i / 19, k = i % 19;
        sx[m][k] = x[(size_t)(n0 + m) * 19 + k];
    }
    __syncthreads();
    float wr[18];
    #pragma unroll
    for (int k = 0; k < 18; ++k) wr[k] = W[k * 256 + tid];
    float bv = bias[tid];
    #pragma unroll
    for (int m = 0; m < 8; ++m) {
        float acc = bv;
        #pragma unroll
        for (int k = 0; k < 18; ++k) acc = fmaf(sx[m][k + 1], wr[k], acc);
        out[(size_t)(n0 + m) * 256 + tid] = __float2bfloat16(fmaxf(acc, 0.f));
    }
}

// ---------------- MFMA bf16 GEMM ----------------
// C = relu(A1@W1 [+ A2@W2] + bias), A panels bf16, WT = [N][Ktot] bf16 (transposed).
// Tile 128x128, BK=32, 4 waves (2x2 of 64x64). Fragment-linear LDS:
// A-block m16 (16 rows x 32 k) at  m16*1024 + lane*16 ; B-block n16 at 8192 + n16*1024 + lane*16.
// If vdot != null: dotout[row] += sum_col relu(.)*vdot[col] (atomic), C unused.
__global__ __launch_bounds__(256) void k_mgemm(
    const bf16* __restrict__ A1, int lda1, int K1,
    const bf16* __restrict__ A2, int lda2, int K2,
    const bf16* __restrict__ WT,
    const float* __restrict__ bias,
    bf16* __restrict__ C, int ldc, int M,
    const float* __restrict__ vdot, float* __restrict__ dotout)
{
    __shared__ char lds[16384] __attribute__((aligned(16)));
    const int tid  = threadIdx.x;
    const int lane = tid & 63;
    const int wid  = tid >> 6;
    const int wm   = wid >> 1, wn = wid & 1;
    const int row0 = blockIdx.y * 128;
    const int col0 = blockIdx.x * 128;
    const int Ktot = K1 + K2;
    const int lmod = lane & 15;
    const int ldiv = lane >> 4;

    f32x4 acc[4][4] = {};

    const bool doA  = (wid < 2);
    const int cbase = (wid & 1) * 4;

    for (int kb = 0; kb < Ktot; kb += 32) {
        __syncthreads();
        if (doA) {
            const bf16* Ap; int lda, kk;
            if (kb < K1) { Ap = A1; lda = lda1; kk = kb; }
            else         { Ap = A2; lda = lda2; kk = kb - K1; }
            int kcol = kk + ldiv * 8;
            #pragma unroll
            for (int c = 0; c < 4; ++c) {
                int chunk = cbase + c;
                int row = row0 + chunk * 16 + lmod;
                row = row < M ? row : M - 1;
                gload16(Ap + (size_t)row * lda + kcol, lds + chunk * 1024);
            }
        } else {
            int kcol = kb + ldiv * 8;
            #pragma unroll
            for (int c = 0; c < 4; ++c) {
                int chunk = cbase + c;
                int col = col0 + chunk * 16 + lmod;
                gload16(WT + (size_t)col * Ktot + kcol, lds + 8192 + chunk * 1024);
            }
        }
        __syncthreads();
        bfrag a[4], b[4];
        #pragma unroll
        for (int i = 0; i < 4; ++i)
            a[i] = *(const bfrag*)(lds + (wm * 4 + i) * 1024 + lane * 16);
        #pragma unroll
        for (int i = 0; i < 4; ++i)
            b[i] = *(const bfrag*)(lds + 8192 + (wn * 4 + i) * 1024 + lane * 16);
        #pragma unroll
        for (int mi = 0; mi < 4; ++mi)
            #pragma unroll
            for (int ni = 0; ni < 4; ++ni)
                acc[mi][ni] = __builtin_amdgcn_mfma_f32_16x16x32_bf16(a[mi], b[ni], acc[mi][ni], 0, 0, 0);
    }

    // epilogue: C/D frag layout col = lane&15, row = (lane>>4)*4 + r
    float bv[4], vv[4];
    #pragma unroll
    for (int ni = 0; ni < 4; ++ni) {
        int colv = col0 + wn * 64 + ni * 16 + lmod;
        bv[ni] = bias ? bias[colv] : 0.f;
        vv[ni] = vdot ? vdot[colv] : 0.f;
    }

    if (vdot) {
        #pragma unroll
        for (int mi = 0; mi < 4; ++mi) {
            #pragma unroll
            for (int r = 0; r < 4; ++r) {
                int row = row0 + wm * 64 + mi * 16 + ldiv * 4 + r;
                float part = 0.f;
                #pragma unroll
                for (int ni = 0; ni < 4; ++ni)
                    part = fmaf(fmaxf(acc[mi][ni][r] + bv[ni], 0.f), vv[ni], part);
                #pragma unroll
                for (int d = 1; d < 16; d <<= 1) part += __shfl_xor(part, d, 64);
                if (lmod == 0 && row < M) atomicAdd(&dotout[row], part);
            }
        }
        return;
    }

    #pragma unroll
    for (int mi = 0; mi < 4; ++mi) {
        int rowb = row0 + wm * 64 + mi * 16 + ldiv * 4;
        #pragma unroll
        for (int ni = 0; ni < 4; ++ni) {
            int col = col0 + wn * 64 + ni * 16 + lmod;
            #pragma unroll
            for (int r = 0; r < 4; ++r) {
                int row = rowb + r;
                if (row < M)
                    C[(size_t)row * ldc + col] = __float2bfloat16(fmaxf(acc[mi][ni][r] + bv[ni], 0.f));
            }
        }
    }
}

// ---------------- GAT (scalar feature, wave per node, 4 channels/lane) ----------------
__global__ __launch_bounds__(256) void k_gat(
    const float* __restrict__ x,
    const int* __restrict__ rp, const int* __restrict__ col,
    const float* __restrict__ gw, const float* __restrict__ gas,
    const float* __restrict__ gad, const float* __restrict__ gb,
    bf16* __restrict__ x1, int outcol)
{
    int lane = threadIdx.x & 63;
    int node = blockIdx.x * 4 + (threadIdx.x >> 6);
    if (node >= NN) return;
    int beg = rp[node], end = rp[node + 1];
    float bias = gb[0];
    float res;
    if (end == beg) {
        res = fmaxf(bias, 0.f);
    } else {
        float maxa = -3.4e38f, mina = 3.4e38f;
        for (int e = beg + lane; e < end; e += 64) {
            float a = x[(size_t)col[e] * 19];
            maxa = fmaxf(maxa, a);
            mina = fminf(mina, a);
        }
        #pragma unroll
        for (int d = 32; d >= 1; d >>= 1) {
            maxa = fmaxf(maxa, __shfl_xor(maxa, d, 64));
            mina = fminf(mina, __shfl_xor(mina, d, 64));
        }
        float b = x[(size_t)node * 19];
        float w[4], u[4], cc[4];
        #pragma unroll
        for (int j = 0; j < 4; ++j) {
            float wv = gw[lane * 4 + j];
            w[j]  = wv;
            u[j]  = wv * gas[lane * 4 + j];
            cc[j] = b * wv * gad[lane * 4 + j];
        }
        float m[4], s[4], t[4];
        #pragma unroll
        for (int j = 0; j < 4; ++j) {
            float sel = (u[j] >= 0.f) ? maxa : mina;   // monotone -> exact segment max
            float mm = fmaf(sel, u[j], cc[j]);
            m[j] = (mm >= 0.f) ? mm : 0.2f * mm;
            s[j] = 0.f; t[j] = 0.f;
        }
        for (int e = beg; e < end; ++e) {
            float a = x[(size_t)col[e] * 19];
            #pragma unroll
            for (int j = 0; j < 4; ++j) {
                float al = fmaf(a, u[j], cc[j]);
                al = (al >= 0.f) ? al : 0.2f * al;
                float p = __expf(al - m[j]);
                s[j] += p;
                t[j] += p * a;
            }
        }
        float part = 0.f;
        #pragma unroll
        for (int j = 0; j < 4; ++j) part += w[j] * t[j] / (s[j] + 1e-16f);
        #pragma unroll
        for (int d = 32; d >= 1; d >>= 1) part += __shfl_xor(part, d, 64);
        res = fmaxf(part * (1.f / 256.f) + bias, 0.f);
    }
    if (lane == 0) x1[(size_t)node * LDX + outcol] = __float2bfloat16(res);
}

// ---------------- SAGE mean-aggregate (bf16, wave per node, 16B gathers) ----------------
__global__ __launch_bounds__(256) void k_sage_agg(
    const bf16* __restrict__ x1, const int* __restrict__ rp, const int* __restrict__ col,
    bf16* __restrict__ agg)
{
    int lane = threadIdx.x & 63;
    int node = blockIdx.x * 4 + (threadIdx.x >> 6);
    if (node >= NN) return;
    int beg = rp[node], end = rp[node + 1];
    float inv = 1.f / fmaxf((float)(end - beg), 1.f);
    if (lane >= 36) return;   // 36 lanes x 8 bf16 = 288 cols
    float s0=0,s1=0,s2=0,s3=0,s4=0,s5=0,s6=0,s7=0;
    for (int e = beg; e < end; ++e) {
        const uint4 v = *(const uint4*)(x1 + (size_t)col[e] * LDX + lane * 8);
        s0 += b2f(v.x); s1 += b2f(v.x >> 16);
        s2 += b2f(v.y); s3 += b2f(v.y >> 16);
        s4 += b2f(v.z); s5 += b2f(v.z >> 16);
        s6 += b2f(v.w); s7 += b2f(v.w >> 16);
    }
    uint4 o;
    o.x = (unsigned)f2b(s0 * inv) | ((unsigned)f2b(s1 * inv) << 16);
    o.y = (unsigned)f2b(s2 * inv) | ((unsigned)f2b(s3 * inv) << 16);
    o.z = (unsigned)f2b(s4 * inv) | ((unsigned)f2b(s5 * inv) << 16);
    o.w = (unsigned)f2b(s6 * inv) | ((unsigned)f2b(s7 * inv) << 16);
    *(uint4*)(agg + (size_t)node * LDX + lane * 8) = o;
}

// ---------------- finalize: dots + bias -> float32 out ----------------
__global__ void k_final(const float* __restrict__ dots,
                        const float* __restrict__ b6, const float* __restrict__ b7,
                        float* __restrict__ out) {
    int i = blockIdx.x * 256 + threadIdx.x;
    if (i >= 2 * NN) return;
    float b = (i < NN) ? b6[0] : b7[0];
    out[i] = dots[i] + b;
}

// ---------------- weight repacks: fp32 [K][N] -> bf16 [N][K] ----------------
__global__ void k_wt(const float* __restrict__ W, bf16* __restrict__ WT, int K, int N) {
    int idx = blockIdx.x * 256 + threadIdx.x;
    if (idx >= K * N) return;
    int n = idx / K, k = idx % K;
    WT[idx] = __float2bfloat16(W[k * N + n]);
}

// SAGE concat: WT [384][576]; k<288 -> wl panel, else wr; kk<259 real rows, else 0.
__global__ void k_wtsage(const float* __restrict__ wl0, const float* __restrict__ wl1,
                         const float* __restrict__ wl2, const float* __restrict__ wr0,
                         const float* __restrict__ wr1, const float* __restrict__ wr2,
                         bf16* __restrict__ WT) {
    int idx = blockIdx.x * 256 + threadIdx.x;
    if (idx >= 384 * 576) return;
    int n = idx / 576, k = idx % 576;
    int half = k / 288, kk = k % 288;
    float v = 0.f;
    if (kk < 259) {
        const float* s = half ? (n < 128 ? wr0 : n < 256 ? wr1 : wr2)
                              : (n < 128 ? wl0 : n < 256 ? wl1 : wl2);
        v = s[kk * 128 + (n & 127)];
    }
    WT[idx] = __float2bfloat16(v);
}

// c21: WT [256][576]
__global__ void k_wtc21(const float* __restrict__ wl, const float* __restrict__ wr,
                        bf16* __restrict__ WT) {
    int idx = blockIdx.x * 256 + threadIdx.x;
    if (idx >= 256 * 576) return;
    int n = idx / 576, k = idx % 576;
    int half = k / 288, kk = k % 288;
    float v = 0.f;
    if (kk < 259) v = (half ? wr : wl)[kk * 256 + n];
    WT[idx] = __float2bfloat16(v);
}

// zero x1 pad cols 256..287 (GATs overwrite 256..258 afterwards)
__global__ void k_padx1(bf16* __restrict__ x1) {
    int idx = blockIdx.x * 256 + threadIdx.x;
    if (idx >= NN * 32) return;
    int node = idx >> 5, c = idx & 31;
    x1[(size_t)node * LDX + 256 + c] = __float2bfloat16(0.f);
}

extern "C" void kernel_launch(void* const* d_in, const int* in_sizes, int n_in,
                              void* d_out, int out_size, void* d_ws, size_t ws_size,
                              hipStream_t stream)
{
    (void)in_sizes; (void)n_in; (void)out_size; (void)ws_size;
    const float* x      = (const float*)d_in[0];
    const float* fc1_w  = (const float*)d_in[1];
    const float* fc1_b  = (const float*)d_in[2];
    const float* fc2_w  = (const float*)d_in[3];
    const float* fc2_b  = (const float*)d_in[4];
    const float* fc3_w  = (const float*)d_in[5];
    const float* fc3_b  = (const float*)d_in[6];
    const float* g_w[3]  = {(const float*)d_in[7],  (const float*)d_in[11], (const float*)d_in[15]};
    const float* g_as[3] = {(const float*)d_in[8],  (const float*)d_in[12], (const float*)d_in[16]};
    const float* g_ad[3] = {(const float*)d_in[9],  (const float*)d_in[13], (const float*)d_in[17]};
    const float* g_b[3]  = {(const float*)d_in[10], (const float*)d_in[14], (const float*)d_in[18]};
    const float* sg_wl[3] = {(const float*)d_in[19], (const float*)d_in[21], (const float*)d_in[23]};
    const float* sg_wr[3] = {(const float*)d_in[20], (const float*)d_in[22], (const float*)d_in[24]};
    const float* c21_wl = (const float*)d_in[25];
    const float* c21_wr = (const float*)d_in[26];
    const float* fc4_w  = (const float*)d_in[27];
    const float* fc4_b  = (const float*)d_in[28];
    const float* fc4n_w = (const float*)d_in[29];
    const float* fc4n_b = (const float*)d_in[30];
    const float* fc5_w  = (const float*)d_in[31];
    const float* fc5_b  = (const float*)d_in[32];
    const float* fc6_w  = (const float*)d_in[33];
    const float* fc6_b  = (const float*)d_in[34];
    const float* fc7_w  = (const float*)d_in[35];
    const float* fc7_b  = (const float*)d_in[36];
    const int* eidx[4] = {(const int*)d_in[37], (const int*)d_in[38], (const int*)d_in[39], (const int*)d_in[40]};
    const int  ecnt[4] = {EA, EA, EB, EB};

    // ---- workspace layout: bf16 section, then fp32, then ints (~106 MB) ----
    bf16* bws = (bf16*)d_ws;
    size_t off = 0;
    bf16* x1    = bws + off; off += (size_t)NN * LDX;   // [x3 | p1 p2 p3 | pad] bf16
    bf16* bufA  = bws + off; off += (size_t)NN * LDX;   // h1 / agg
    bf16* bufB  = bws + off; off += (size_t)NN * 384;   // h2 / xn / s
    bf16* fc2T  = bws + off; off += 256 * 256;
    bf16* fc3T  = bws + off; off += 256 * 256;
    bf16* fc4T  = bws + off; off += 256 * 384;
    bf16* fc4nT = bws + off; off += 256 * 256;
    bf16* fc5T  = bws + off; off += 256 * 256;
    bf16* sageT = bws + off; off += 384 * 576;
    bf16* c21T  = bws + off; off += 256 * 576;
    float* dots = (float*)(bws + off);                  // [y | xn] pre-bias dots
    int* deg4 = (int*)(dots + 2 * NN);
    int* rp4  = deg4 + 4 * NN;
    int* cur4 = rp4 + 4 * (NN + 1);
    int* colx = cur4 + 4 * NN;
    int* colg[4] = {colx, colx + EA, colx + 2 * EA, colx + 2 * EA + EB};

    float* outy = (float*)d_out;

    // ---- zero deg counters + dot scratch ----
    k_zero<<<(4 * NN + 255) / 256, 256, 0, stream>>>((unsigned int*)deg4, 4 * NN);
    k_zero<<<(2 * NN + 255) / 256, 256, 0, stream>>>((unsigned int*)dots, 2 * NN);

    // ---- CSR build (0=r1, 1=r2, 2=r3, 3=neg) ----
    for (int g = 0; g < 4; ++g)
        k_count<<<(ecnt[g] + 255) / 256, 256, 0, stream>>>(eidx[g] + ecnt[g], ecnt[g], deg4 + g * NN);
    k_scan4<<<4, 1024, 0, stream>>>(deg4, rp4, cur4, NN);
    for (int g = 0; g < 4; ++g)
        k_scatter<<<(ecnt[g] + 255) / 256, 256, 0, stream>>>(eidx[g], eidx[g] + ecnt[g], ecnt[g],
                                                             cur4 + g * NN, colg[g]);

    // ---- weight repacks (fp32 -> transposed bf16) ----
    k_wt<<<(256 * 256 + 255) / 256, 256, 0, stream>>>(fc2_w, fc2T, 256, 256);
    k_wt<<<(256 * 256 + 255) / 256, 256, 0, stream>>>(fc3_w, fc3T, 256, 256);
    k_wt<<<(384 * 256 + 255) / 256, 256, 0, stream>>>(fc4_w, fc4T, 384, 256);
    k_wt<<<(256 * 256 + 255) / 256, 256, 0, stream>>>(fc4n_w, fc4nT, 256, 256);
    k_wt<<<(256 * 256 + 255) / 256, 256, 0, stream>>>(fc5_w, fc5T, 256, 256);
    k_wtsage<<<(384 * 576 + 255) / 256, 256, 0, stream>>>(sg_wl[0], sg_wl[1], sg_wl[2],
                                                          sg_wr[0], sg_wr[1], sg_wr[2], sageT);
    k_wtc21<<<(256 * 576 + 255) / 256, 256, 0, stream>>>(c21_wl, c21_wr, c21T);

    const int gy = (NN + 127) / 128;   // 391
    dim3 g2(2, gy), g3(3, gy);

    // ---- MLP head: fc1 -> fc2 -> fc3 (x1 cols 0..255) ----
    k_fc1<<<NN / 8, 256, 0, stream>>>(x, fc1_w, fc1_b, bufA);
    k_mgemm<<<g2, 256, 0, stream>>>(bufA, 256, 256, nullptr, 0, 0, fc2T, fc2_b, bufB, 256, NN, nullptr, nullptr);
    k_mgemm<<<g2, 256, 0, stream>>>(bufB, 256, 256, nullptr, 0, 0, fc3T, fc3_b, x1, LDX, NN, nullptr, nullptr);
    k_padx1<<<(NN * 32 + 255) / 256, 256, 0, stream>>>(x1);

    // ---- GATs -> x1 cols 256,257,258 ----
    for (int g = 0; g < 3; ++g)
        k_gat<<<NN / 4, 256, 0, stream>>>(x, rp4 + g * (NN + 1), colg[g],
                                          g_w[g], g_as[g], g_ad[g], g_b[g], x1, 256 + g);

    // ---- xn path: neg-SAGE -> c21 -> fc4n(+relu) + fused fc7 dot ----
    k_sage_agg<<<NN / 4, 256, 0, stream>>>(x1, rp4 + 3 * (NN + 1), colg[3], bufA);
    k_mgemm<<<g2, 256, 0, stream>>>(bufA, LDX, 288, x1, LDX, 288, c21T, nullptr, bufB, 256, NN, nullptr, nullptr);
    k_mgemm<<<g2, 256, 0, stream>>>(bufB, 256, 256, nullptr, 0, 0, fc4nT, fc4n_b, nullptr, 0, NN, fc7_w, dots + NN);

    // ---- y path: r3-SAGE (3 layers fused) -> fc4 -> fused fc5+fc6 dot ----
    k_sage_agg<<<NN / 4, 256, 0, stream>>>(x1, rp4 + 2 * (NN + 1), colg[2], bufA);
    k_mgemm<<<g3, 256, 0, stream>>>(bufA, LDX, 288, x1, LDX, 288, sageT, nullptr, bufB, 384, NN, nullptr, nullptr);
    k_mgemm<<<g2, 256, 0, stream>>>(bufB, 384, 384, nullptr, 0, 0, fc4T, fc4_b, bufA, 256, NN, nullptr, nullptr);
    k_mgemm<<<g2, 256, 0, stream>>>(bufA, 256, 256, nullptr, 0, 0, fc5T, fc5_b, nullptr, 0, NN, fc6_w, dots);

    // ---- finalize (fp32 out) ----
    k_final<<<(2 * NN + 255) / 256, 256, 0, stream>>>(dots, fc6_b, fc7_b, outy);
}

// Round 11
// 838.576 us; speedup vs baseline: 2.0226x; 1.0989x over previous
//
#include <hip/hip_runtime.h>
#include <hip/hip_bf16.h>

typedef __hip_bfloat16 bf16;
typedef __attribute__((ext_vector_type(8))) short bfrag;   // 8 bf16 = 4 VGPRs
typedef __attribute__((ext_vector_type(4))) float f32x4;

static constexpr int NN  = 50000;
static constexpr int EA  = 250000;   // r1, r2
static constexpr int EB  = 500000;   // r3, neg
static constexpr int LDX = 288;      // x1/agg row stride in bf16 (576 B, 16B-aligned)

__device__ __forceinline__ float b2f(unsigned int u) { return __uint_as_float((u & 0xffffu) << 16); }
__device__ __forceinline__ unsigned short f2b(float f) {
    bf16 h = __float2bfloat16(f);
    return *reinterpret_cast<unsigned short*>(&h);
}
__device__ __forceinline__ void gload16(const void* g, void* l) {
    __builtin_amdgcn_global_load_lds((const __attribute__((address_space(1))) void*)g,
                                     (__attribute__((address_space(3))) void*)l, 16, 0, 0);
}

// ---------------- utility: zero 32-bit words ----------------
__global__ void k_zero(unsigned int* __restrict__ p, int n) {
    int i = blockIdx.x * 256 + threadIdx.x;
    if (i < n) p[i] = 0u;
}

// ---------------- CSR build ----------------
__global__ void k_count(const int* __restrict__ dst, int E, int* __restrict__ deg) {
    int e = blockIdx.x * blockDim.x + threadIdx.x;
    if (e < E) atomicAdd(&deg[dst[e]], 1);
}

__global__ __launch_bounds__(1024) void k_scan4(const int* __restrict__ deg4,
                                                int* __restrict__ rp4,
                                                int* __restrict__ cur4, int n) {
    const int* deg = deg4 + (size_t)blockIdx.x * n;
    int* rp  = rp4  + (size_t)blockIdx.x * (n + 1);
    int* cur = cur4 + (size_t)blockIdx.x * n;
    __shared__ int wsum[16];
    __shared__ int srun;
    int tid = threadIdx.x;
    int lane = tid & 63, wid = tid >> 6;
    if (tid == 0) srun = 0;
    __syncthreads();
    for (int base = 0; base < n; base += 1024) {
        int i = base + tid;
        int v = (i < n) ? deg[i] : 0;
        int incl = v;
        #pragma unroll
        for (int d = 1; d < 64; d <<= 1) {
            int y = __shfl_up(incl, d, 64);
            if (lane >= d) incl += y;
        }
        if (lane == 63) wsum[wid] = incl;
        __syncthreads();
        if (wid == 0 && lane < 16) {
            int w = wsum[lane];
            #pragma unroll
            for (int d = 1; d < 16; d <<= 1) {
                int y = __shfl_up(w, d, 64);
                if (lane >= d) w += y;
            }
            wsum[lane] = w;
        }
        __syncthreads();
        int run  = srun;
        int woff = (wid > 0) ? wsum[wid - 1] : 0;
        int ex   = run + woff + incl - v;
        if (i < n) { rp[i] = ex; cur[i] = ex; }
        int total = wsum[15];
        __syncthreads();
        if (tid == 0) srun = run + total;
        __syncthreads();
    }
    if (tid == 0) rp[n] = srun;
}

__global__ void k_scatter(const int* __restrict__ src, const int* __restrict__ dst, int E,
                          int* __restrict__ cur, int* __restrict__ col) {
    int e = blockIdx.x * blockDim.x + threadIdx.x;
    if (e < E) {
        int p = atomicAdd(&cur[dst[e]], 1);
        col[p] = src[e];
    }
}

// ---------------- fc1 (K=18, reads x[:,1:19] fp32) -> bf16 out ----------------
__global__ __launch_bounds__(256) void k_fc1(const float* __restrict__ x,
                                             const float* __restrict__ W,
                                             const float* __restrict__ bias,
                                             bf16* __restrict__ out) {
    __shared__ float sx[8][20];
    int tid = threadIdx.x;
    int n0 = blockIdx.x * 8;
    for (int i = tid; i < 8 * 19; i += 256) {
        int m = i / 19, k = i % 19;
        sx[m][k] = x[(size_t)(n0 + m) * 19 + k];
    }
    __syncthreads();
    float wr[18];
    #pragma unroll
    for (int k = 0; k < 18; ++k) wr[k] = W[k * 256 + tid];
    float bv = bias[tid];
    #pragma unroll
    for (int m = 0; m < 8; ++m) {
        float acc = bv;
        #pragma unroll
        for (int k = 0; k < 18; ++k) acc = fmaf(sx[m][k + 1], wr[k], acc);
        out[(size_t)(n0 + m) * 256 + tid] = __float2bfloat16(fmaxf(acc, 0.f));
    }
}

// ---------------- MFMA bf16 GEMM, double-buffered, XCD-swizzled ----------------
// C = relu(A1@W1 [+ A2@W2] + bias); WT = [N][Ktot] bf16. Tile 128x128, BK=32,
// 4 waves (2x2 of 64x64). Staging: 2 x 16KB LDS buffers, fragment-linear layout.
// If vdot != null: dotout[row] += sum_col relu(.)*vdot[col] (atomic), C unused.
__global__ __launch_bounds__(256) void k_mgemm(
    const bf16* __restrict__ A1, int lda1, int K1,
    const bf16* __restrict__ A2, int lda2, int K2,
    const bf16* __restrict__ WT,
    const float* __restrict__ bias,
    bf16* __restrict__ C, int ldc, int M,
    const float* __restrict__ vdot, float* __restrict__ dotout)
{
    __shared__ char lds[36864] __attribute__((aligned(16)));
    const int tid  = threadIdx.x;
    const int lane = tid & 63;
    const int wid  = tid >> 6;
    const int wm   = wid >> 1, wn = wid & 1;
    const int lmod = lane & 15;
    const int ldiv = lane >> 4;

    // bijective XCD swizzle (m204): consecutive logical tiles -> same XCD L2
    const int gx  = gridDim.x;
    const int nwg = gx * gridDim.y;
    const int h   = blockIdx.y * gx + blockIdx.x;
    const int xcd = h & 7, li = h >> 3;
    const int q = nwg >> 3, r = nwg & 7;
    const int t = (xcd < r ? xcd * (q + 1) : r * (q + 1) + (xcd - r) * q) + li;
    const int row0 = (t / gx) * 128;
    const int col0 = (t % gx) * 128;

    const int Ktot = K1 + K2;
    const int nt   = Ktot >> 5;
    const bool doA  = (wid < 2);
    const int cbase = (wid & 1) * 4;

    f32x4 acc[4][4] = {};

    // stage K-step kb into buffer buf (waves 0-1: A panel, waves 2-3: B panel)
    #define STAGE(kb, buf)                                                          \
    {                                                                               \
        char* dst = lds + (buf) * 16384;                                            \
        if (doA) {                                                                  \
            const bf16* Ap; int lda, kk;                                            \
            if ((kb) < K1) { Ap = A1; lda = lda1; kk = (kb); }                      \
            else           { Ap = A2; lda = lda2; kk = (kb) - K1; }                 \
            int kcol = kk + ldiv * 8;                                               \
            _Pragma("unroll")                                                       \
            for (int c = 0; c < 4; ++c) {                                           \
                int chunk = cbase + c;                                              \
                int row = row0 + chunk * 16 + lmod;                                 \
                row = row < M ? row : M - 1;                                        \
                gload16(Ap + (size_t)row * lda + kcol, dst + chunk * 1024);         \
            }                                                                       \
        } else {                                                                    \
            int kcol = (kb) + ldiv * 8;                                             \
            _Pragma("unroll")                                                       \
            for (int c = 0; c < 4; ++c) {                                           \
                int chunk = cbase + c;                                              \
                int col = col0 + chunk * 16 + lmod;                                 \
                gload16(WT + (size_t)col * Ktot + kcol, dst + 8192 + chunk * 1024); \
            }                                                                       \
        }                                                                           \
    }

    STAGE(0, 0);
    __syncthreads();   // drains vmcnt(0): buf0 ready
    for (int s = 0; s < nt; ++s) {
        if (s + 1 < nt) STAGE((s + 1) << 5, (s + 1) & 1);   // prefetch next
        const char* cb = lds + (s & 1) * 16384;
        bfrag a[4], b[4];
        #pragma unroll
        for (int i = 0; i < 4; ++i)
            a[i] = *(const bfrag*)(cb + (wm * 4 + i) * 1024 + lane * 16);
        #pragma unroll
        for (int i = 0; i < 4; ++i)
            b[i] = *(const bfrag*)(cb + 8192 + (wn * 4 + i) * 1024 + lane * 16);
        #pragma unroll
        for (int mi = 0; mi < 4; ++mi)
            #pragma unroll
            for (int ni = 0; ni < 4; ++ni)
                acc[mi][ni] = __builtin_amdgcn_mfma_f32_16x16x32_bf16(a[mi], b[ni], acc[mi][ni], 0, 0, 0);
        __syncthreads();   // drains vmcnt(0)+lgkmcnt: next buffer staged, cur reads done
    }
    #undef STAGE

    // epilogue: C/D frag layout col = lane&15, row = (lane>>4)*4 + r
    float bv[4], vv[4];
    #pragma unroll
    for (int ni = 0; ni < 4; ++ni) {
        int colv = col0 + wn * 64 + ni * 16 + lmod;
        bv[ni] = bias ? bias[colv] : 0.f;
        vv[ni] = vdot ? vdot[colv] : 0.f;
    }

    if (vdot) {
        #pragma unroll
        for (int mi = 0; mi < 4; ++mi) {
            #pragma unroll
            for (int r = 0; r < 4; ++r) {
                int row = row0 + wm * 64 + mi * 16 + ldiv * 4 + r;
                float part = 0.f;
                #pragma unroll
                for (int ni = 0; ni < 4; ++ni)
                    part = fmaf(fmaxf(acc[mi][ni][r] + bv[ni], 0.f), vv[ni], part);
                #pragma unroll
                for (int d = 1; d < 16; d <<= 1) part += __shfl_xor(part, d, 64);
                if (lmod == 0 && row < M) atomicAdd(&dotout[row], part);
            }
        }
        return;
    }

    // repack via LDS (per-wave 64x64 tile, row stride 72 elems) -> uint4 stores
    unsigned short* sm = (unsigned short*)lds + (size_t)wid * 4608;   // 64*72 elems
    #pragma unroll
    for (int mi = 0; mi < 4; ++mi)
        #pragma unroll
        for (int ni = 0; ni < 4; ++ni)
            #pragma unroll
            for (int r = 0; r < 4; ++r) {
                int rl = mi * 16 + ldiv * 4 + r;
                int cl = ni * 16 + lmod;
                sm[rl * 72 + cl] = f2b(fmaxf(acc[mi][ni][r] + bv[ni], 0.f));
            }
    // same-wave readback (no barrier needed): 8 rows x 8 chunks per iter
    #pragma unroll
    for (int it = 0; it < 8; ++it) {
        int rl = it * 8 + (lane >> 3);
        int ck = lane & 7;
        uint4 v = *(const uint4*)(sm + rl * 72 + ck * 8);
        int grow = row0 + wm * 64 + rl;
        if (grow < M)
            *(uint4*)(C + (size_t)grow * ldc + col0 + wn * 64 + ck * 8) = v;
    }
}

// ---------------- GAT (scalar feature, wave per node, 4 channels/lane) ----------------
__global__ __launch_bounds__(256) void k_gat(
    const float* __restrict__ x,
    const int* __restrict__ rp, const int* __restrict__ col,
    const float* __restrict__ gw, const float* __restrict__ gas,
    const float* __restrict__ gad, const float* __restrict__ gb,
    bf16* __restrict__ x1, int outcol)
{
    int lane = threadIdx.x & 63;
    int node = blockIdx.x * 4 + (threadIdx.x >> 6);
    if (node >= NN) return;
    int beg = rp[node], end = rp[node + 1];
    float bias = gb[0];
    float res;
    if (end == beg) {
        res = fmaxf(bias, 0.f);
    } else {
        float maxa = -3.4e38f, mina = 3.4e38f;
        for (int e = beg + lane; e < end; e += 64) {
            float a = x[(size_t)col[e] * 19];
            maxa = fmaxf(maxa, a);
            mina = fminf(mina, a);
        }
        #pragma unroll
        for (int d = 32; d >= 1; d >>= 1) {
            maxa = fmaxf(maxa, __shfl_xor(maxa, d, 64));
            mina = fminf(mina, __shfl_xor(mina, d, 64));
        }
        float b = x[(size_t)node * 19];
        float w[4], u[4], cc[4];
        #pragma unroll
        for (int j = 0; j < 4; ++j) {
            float wv = gw[lane * 4 + j];
            w[j]  = wv;
            u[j]  = wv * gas[lane * 4 + j];
            cc[j] = b * wv * gad[lane * 4 + j];
        }
        float m[4], s[4], t[4];
        #pragma unroll
        for (int j = 0; j < 4; ++j) {
            float sel = (u[j] >= 0.f) ? maxa : mina;   // monotone -> exact segment max
            float mm = fmaf(sel, u[j], cc[j]);
            m[j] = (mm >= 0.f) ? mm : 0.2f * mm;
            s[j] = 0.f; t[j] = 0.f;
        }
        for (int e = beg; e < end; ++e) {
            float a = x[(size_t)col[e] * 19];
            #pragma unroll
            for (int j = 0; j < 4; ++j) {
                float al = fmaf(a, u[j], cc[j]);
                al = (al >= 0.f) ? al : 0.2f * al;
                float p = __expf(al - m[j]);
                s[j] += p;
                t[j] += p * a;
            }
        }
        float part = 0.f;
        #pragma unroll
        for (int j = 0; j < 4; ++j) part += w[j] * t[j] / (s[j] + 1e-16f);
        #pragma unroll
        for (int d = 32; d >= 1; d >>= 1) part += __shfl_xor(part, d, 64);
        res = fmaxf(part * (1.f / 256.f) + bias, 0.f);
    }
    if (lane == 0) x1[(size_t)node * LDX + outcol] = __float2bfloat16(res);
}

// ---------------- SAGE mean-aggregate (bf16, wave per node, 16B gathers) ----------------
__global__ __launch_bounds__(256) void k_sage_agg(
    const bf16* __restrict__ x1, const int* __restrict__ rp, const int* __restrict__ col,
    bf16* __restrict__ agg)
{
    int lane = threadIdx.x & 63;
    int node = blockIdx.x * 4 + (threadIdx.x >> 6);
    if (node >= NN) return;
    int beg = rp[node], end = rp[node + 1];
    float inv = 1.f / fmaxf((float)(end - beg), 1.f);
    if (lane >= 36) return;   // 36 lanes x 8 bf16 = 288 cols
    float s0=0,s1=0,s2=0,s3=0,s4=0,s5=0,s6=0,s7=0;
    for (int e = beg; e < end; ++e) {
        const uint4 v = *(const uint4*)(x1 + (size_t)col[e] * LDX + lane * 8);
        s0 += b2f(v.x); s1 += b2f(v.x >> 16);
        s2 += b2f(v.y); s3 += b2f(v.y >> 16);
        s4 += b2f(v.z); s5 += b2f(v.z >> 16);
        s6 += b2f(v.w); s7 += b2f(v.w >> 16);
    }
    uint4 o;
    o.x = (unsigned)f2b(s0 * inv) | ((unsigned)f2b(s1 * inv) << 16);
    o.y = (unsigned)f2b(s2 * inv) | ((unsigned)f2b(s3 * inv) << 16);
    o.z = (unsigned)f2b(s4 * inv) | ((unsigned)f2b(s5 * inv) << 16);
    o.w = (unsigned)f2b(s6 * inv) | ((unsigned)f2b(s7 * inv) << 16);
    *(uint4*)(agg + (size_t)node * LDX + lane * 8) = o;
}

// ---------------- finalize: dots + bias -> float32 out ----------------
__global__ void k_final(const float* __restrict__ dots,
                        const float* __restrict__ b6, const float* __restrict__ b7,
                        float* __restrict__ out) {
    int i = blockIdx.x * 256 + threadIdx.x;
    if (i >= 2 * NN) return;
    float b = (i < NN) ? b6[0] : b7[0];
    out[i] = dots[i] + b;
}

// ---------------- weight repacks: fp32 [K][N] -> bf16 [N][K] ----------------
__global__ void k_wt(const float* __restrict__ W, bf16* __restrict__ WT, int K, int N) {
    int idx = blockIdx.x * 256 + threadIdx.x;
    if (idx >= K * N) return;
    int n = idx / K, k = idx % K;
    WT[idx] = __float2bfloat16(W[k * N + n]);
}

// SAGE concat: WT [384][576]; k<288 -> wl panel, else wr; kk<259 real rows, else 0.
__global__ void k_wtsage(const float* __restrict__ wl0, const float* __restrict__ wl1,
                         const float* __restrict__ wl2, const float* __restrict__ wr0,
                         const float* __restrict__ wr1, const float* __restrict__ wr2,
                         bf16* __restrict__ WT) {
    int idx = blockIdx.x * 256 + threadIdx.x;
    if (idx >= 384 * 576) return;
    int n = idx / 576, k = idx % 576;
    int half = k / 288, kk = k % 288;
    float v = 0.f;
    if (kk < 259) {
        const float* s = half ? (n < 128 ? wr0 : n < 256 ? wr1 : wr2)
                              : (n < 128 ? wl0 : n < 256 ? wl1 : wl2);
        v = s[kk * 128 + (n & 127)];
    }
    WT[idx] = __float2bfloat16(v);
}

// c21: WT [256][576]
__global__ void k_wtc21(const float* __restrict__ wl, const float* __restrict__ wr,
                        bf16* __restrict__ WT) {
    int idx = blockIdx.x * 256 + threadIdx.x;
    if (idx >= 256 * 576) return;
    int n = idx / 576, k = idx % 576;
    int half = k / 288, kk = k % 288;
    float v = 0.f;
    if (kk < 259) v = (half ? wr : wl)[kk * 256 + n];
    WT[idx] = __float2bfloat16(v);
}

// zero x1 pad cols 256..287 (GATs overwrite 256..258 afterwards)
__global__ void k_padx1(bf16* __restrict__ x1) {
    int idx = blockIdx.x * 256 + threadIdx.x;
    if (idx >= NN * 32) return;
    int node = idx >> 5, c = idx & 31;
    x1[(size_t)node * LDX + 256 + c] = __float2bfloat16(0.f);
}

extern "C" void kernel_launch(void* const* d_in, const int* in_sizes, int n_in,
                              void* d_out, int out_size, void* d_ws, size_t ws_size,
                              hipStream_t stream)
{
    (void)in_sizes; (void)n_in; (void)out_size; (void)ws_size;
    const float* x      = (const float*)d_in[0];
    const float* fc1_w  = (const float*)d_in[1];
    const float* fc1_b  = (const float*)d_in[2];
    const float* fc2_w  = (const float*)d_in[3];
    const float* fc2_b  = (const float*)d_in[4];
    const float* fc3_w  = (const float*)d_in[5];
    const float* fc3_b  = (const float*)d_in[6];
    const float* g_w[3]  = {(const float*)d_in[7],  (const float*)d_in[11], (const float*)d_in[15]};
    const float* g_as[3] = {(const float*)d_in[8],  (const float*)d_in[12], (const float*)d_in[16]};
    const float* g_ad[3] = {(const float*)d_in[9],  (const float*)d_in[13], (const float*)d_in[17]};
    const float* g_b[3]  = {(const float*)d_in[10], (const float*)d_in[14], (const float*)d_in[18]};
    const float* sg_wl[3] = {(const float*)d_in[19], (const float*)d_in[21], (const float*)d_in[23]};
    const float* sg_wr[3] = {(const float*)d_in[20], (const float*)d_in[22], (const float*)d_in[24]};
    const float* c21_wl = (const float*)d_in[25];
    const float* c21_wr = (const float*)d_in[26];
    const float* fc4_w  = (const float*)d_in[27];
    const float* fc4_b  = (const float*)d_in[28];
    const float* fc4n_w = (const float*)d_in[29];
    const float* fc4n_b = (const float*)d_in[30];
    const float* fc5_w  = (const float*)d_in[31];
    const float* fc5_b  = (const float*)d_in[32];
    const float* fc6_w  = (const float*)d_in[33];
    const float* fc6_b  = (const float*)d_in[34];
    const float* fc7_w  = (const float*)d_in[35];
    const float* fc7_b  = (const float*)d_in[36];
    const int* eidx[4] = {(const int*)d_in[37], (const int*)d_in[38], (const int*)d_in[39], (const int*)d_in[40]};
    const int  ecnt[4] = {EA, EA, EB, EB};

    // ---- workspace layout: bf16 section, then fp32, then ints (~106 MB) ----
    bf16* bws = (bf16*)d_ws;
    size_t off = 0;
    bf16* x1    = bws + off; off += (size_t)NN * LDX;   // [x3 | p1 p2 p3 | pad] bf16
    bf16* bufA  = bws + off; off += (size_t)NN * LDX;   // h1 / agg
    bf16* bufB  = bws + off; off += (size_t)NN * 384;   // h2 / xn / s
    bf16* fc2T  = bws + off; off += 256 * 256;
    bf16* fc3T  = bws + off; off += 256 * 256;
    bf16* fc4T  = bws + off; off += 256 * 384;
    bf16* fc4nT = bws + off; off += 256 * 256;
    bf16* fc5T  = bws + off; off += 256 * 256;
    bf16* sageT = bws + off; off += 384 * 576;
    bf16* c21T  = bws + off; off += 256 * 576;
    float* dots = (float*)(bws + off);                  // [y | xn] pre-bias dots
    int* deg4 = (int*)(dots + 2 * NN);
    int* rp4  = deg4 + 4 * NN;
    int* cur4 = rp4 + 4 * (NN + 1);
    int* colx = cur4 + 4 * NN;
    int* colg[4] = {colx, colx + EA, colx + 2 * EA, colx + 2 * EA + EB};

    float* outy = (float*)d_out;

    // ---- zero deg counters + dot scratch ----
    k_zero<<<(4 * NN + 255) / 256, 256, 0, stream>>>((unsigned int*)deg4, 4 * NN);
    k_zero<<<(2 * NN + 255) / 256, 256, 0, stream>>>((unsigned int*)dots, 2 * NN);

    // ---- CSR build (0=r1, 1=r2, 2=r3, 3=neg) ----
    for (int g = 0; g < 4; ++g)
        k_count<<<(ecnt[g] + 255) / 256, 256, 0, stream>>>(eidx[g] + ecnt[g], ecnt[g], deg4 + g * NN);
    k_scan4<<<4, 1024, 0, stream>>>(deg4, rp4, cur4, NN);
    for (int g = 0; g < 4; ++g)
        k_scatter<<<(ecnt[g] + 255) / 256, 256, 0, stream>>>(eidx[g], eidx[g] + ecnt[g], ecnt[g],
                                                             cur4 + g * NN, colg[g]);

    // ---- weight repacks (fp32 -> transposed bf16) ----
    k_wt<<<(256 * 256 + 255) / 256, 256, 0, stream>>>(fc2_w, fc2T, 256, 256);
    k_wt<<<(256 * 256 + 255) / 256, 256, 0, stream>>>(fc3_w, fc3T, 256, 256);
    k_wt<<<(384 * 256 + 255) / 256, 256, 0, stream>>>(fc4_w, fc4T, 384, 256);
    k_wt<<<(256 * 256 + 255) / 256, 256, 0, stream>>>(fc4n_w, fc4nT, 256, 256);
    k_wt<<<(256 * 256 + 255) / 256, 256, 0, stream>>>(fc5_w, fc5T, 256, 256);
    k_wtsage<<<(384 * 576 + 255) / 256, 256, 0, stream>>>(sg_wl[0], sg_wl[1], sg_wl[2],
                                                          sg_wr[0], sg_wr[1], sg_wr[2], sageT);
    k_wtc21<<<(256 * 576 + 255) / 256, 256, 0, stream>>>(c21_wl, c21_wr, c21T);

    const int gy = (NN + 127) / 128;   // 391
    dim3 g2(2, gy), g3(3, gy);

    // ---- MLP head: fc1 -> fc2 -> fc3 (x1 cols 0..255) ----
    k_fc1<<<NN / 8, 256, 0, stream>>>(x, fc1_w, fc1_b, bufA);
    k_mgemm<<<g2, 256, 0, stream>>>(bufA, 256, 256, nullptr, 0, 0, fc2T, fc2_b, bufB, 256, NN, nullptr, nullptr);
    k_mgemm<<<g2, 256, 0, stream>>>(bufB, 256, 256, nullptr, 0, 0, fc3T, fc3_b, x1, LDX, NN, nullptr, nullptr);
    k_padx1<<<(NN * 32 + 255) / 256, 256, 0, stream>>>(x1);

    // ---- GATs -> x1 cols 256,257,258 ----
    for (int g = 0; g < 3; ++g)
        k_gat<<<NN / 4, 256, 0, stream>>>(x, rp4 + g * (NN + 1), colg[g],
                                          g_w[g], g_as[g], g_ad[g], g_b[g], x1, 256 + g);

    // ---- xn path: neg-SAGE -> c21 -> fc4n(+relu) + fused fc7 dot ----
    k_sage_agg<<<NN / 4, 256, 0, stream>>>(x1, rp4 + 3 * (NN + 1), colg[3], bufA);
    k_mgemm<<<g2, 256, 0, stream>>>(bufA, LDX, 288, x1, LDX, 288, c21T, nullptr, bufB, 256, NN, nullptr, nullptr);
    k_mgemm<<<g2, 256, 0, stream>>>(bufB, 256, 256, nullptr, 0, 0, fc4nT, fc4n_b, nullptr, 0, NN, fc7_w, dots + NN);

    // ---- y path: r3-SAGE (3 layers fused) -> fc4 -> fused fc5+fc6 dot ----
    k_sage_agg<<<NN / 4, 256, 0, stream>>>(x1, rp4 + 2 * (NN + 1), colg[2], bufA);
    k_mgemm<<<g3, 256, 0, stream>>>(bufA, LDX, 288, x1, LDX, 288, sageT, nullptr, bufB, 384, NN, nullptr, nullptr);
    k_mgemm<<<g2, 256, 0, stream>>>(bufB, 384, 384, nullptr, 0, 0, fc4T, fc4_b, bufA, 256, NN, nullptr, nullptr);
    k_mgemm<<<g2, 256, 0, stream>>>(bufA, 256, 256, nullptr, 0, 0, fc5T, fc5_b, nullptr, 0, NN, fc6_w, dots);

    // ---- finalize (fp32 out) ----
    k_final<<<(2 * NN + 255) / 256, 256, 0, stream>>>(dots, fc6_b, fc7_b, outy);
}